// Round 8
// baseline (164.085 us; speedup 1.0000x reference)
//
#include <hip/hip_runtime.h>
#include <hip/hip_bf16.h>

// Math (validated rounds 2-7, all passed): softmax rows sum to 1 =>
//   out = (x @ WvSum) @ WoSum + bo,  Wq/Wk dead.
//   WvSum[k][d] = sum_h Wv[k][h*64+d]  (1024x64)
//   WoSum[d][e] = sum_h Wo[h*64+d][e]  (64x1024)
// Numerics: single-product fp16 MFMA (rounds 6/7: absmax 0.125, passed).
// Round-7 counters: VGPR 32 (compiler sank prefetch rings again), WRITE 87MB
// (NT-store amplification), HBM 32%, all pipes idle -> latency-bound.
// This round:
//   - TLP instead of ILP: 512-thr blocks / 8 waves, K split 8x in phase 1,
//     cols split 8x in phase 2, launch_bounds(512,8) -> 32 waves/CU.
//   - phase-2 operand swap: mfma(WoS_frag, tmp_frag) -> D lanes hold 4
//     consecutive e-cols of ONE x-row => float4 stores (was 4B scatter).
//     BoF layout and Af LDS read are IDENTICAL under the swap (A/B frag
//     mappings are mutual transposes) - only the store indexing changes.
//   - NT stores reverted (L2 write merging wanted).

typedef _Float16 half8 __attribute__((ext_vector_type(8)));
typedef float f32x4 __attribute__((ext_vector_type(4)));

__device__ __forceinline__ half8 cvt8(float4 a, float4 b) {
  half8 h;
  h[0] = (_Float16)a.x; h[1] = (_Float16)a.y;
  h[2] = (_Float16)a.z; h[3] = (_Float16)a.w;
  h[4] = (_Float16)b.x; h[5] = (_Float16)b.y;
  h[6] = (_Float16)b.z; h[7] = (_Float16)b.w;
  return h;
}

// ---------------- prep: weight sums -> fp16 B-frags in MFMA lane order -------
// (verbatim rounds 6/7 — verified)
// BvF (half8 idx): (s*4 + ctg)*64 + lane  holds WvSum[k=s*32+(l>>4)*8+j][d=ctg*16+(l&15)]
// BoF (half8 idx): (g*2 + kk)*64 + lane   holds WoSum[k=kk*32+(l>>4)*8+j][e=g*16+(l&15)]
__global__ __launch_bounds__(256) void prep(const float* __restrict__ Wv,
                                            const float* __restrict__ Wo,
                                            _Float16* __restrict__ BvF,
                                            _Float16* __restrict__ BoF) {
  const int b = blockIdx.x, t = threadIdx.x;
  const int l = t & 63, lr = l & 15, lk = (l >> 4) << 3;
  if (b < 32) {                 // Bv frags, k-slice s = b
    const int s = b, ctg = t >> 6;
    const int d = (ctg << 4) + lr;
    const int k0 = (s << 5) + lk;
    float sum[8] = {};
#pragma unroll
    for (int h = 0; h < 16; ++h)
#pragma unroll
      for (int j = 0; j < 8; ++j)
        sum[j] += Wv[(k0 + j) * 1024 + h * 64 + d];
    half8 hv;
#pragma unroll
    for (int j = 0; j < 8; ++j) hv[j] = (_Float16)sum[j];
    ((half8*)BvF)[(s * 4 + ctg) * 64 + l] = hv;
  } else {                      // Bo frags, col-frag g = b-32
    const int g = b - 32;
    const int kk = t >> 7, jh = (t >> 6) & 1;
    const int e = (g << 4) + lr;
    const int kb = (kk << 5) + lk + (jh << 2);
    float sum[4] = {};
#pragma unroll
    for (int h = 0; h < 16; ++h)
#pragma unroll
      for (int j = 0; j < 4; ++j)
        sum[j] += Wo[(h * 64 + kb + j) * 1024 + e];
    _Float16 hv[4];
#pragma unroll
    for (int j = 0; j < 4; ++j) hv[j] = (_Float16)sum[j];
    *(uint2*)&BoF[(((g * 2 + kk) * 64 + l) << 3) + (jh << 2)] =
        *(const uint2*)hv;
  }
}

// ---------------- fused: out_strip = (x_strip @ WvS) @ WoS + bo --------------
// 512 thr = 8 waves (w), strip = 16 rows, grid 1024 -> 32 waves/CU.
// Phase1: wave w covers K-slice w*128..+127 (4 chunks of 32), all 64 cols.
// Phase2: wave w covers cols w*128..+127 (8 col-frags), float4 stores.
__global__ __launch_bounds__(512, 8) void fused(const float* __restrict__ x,
                                                const _Float16* __restrict__ BvF,
                                                const _Float16* __restrict__ BoF,
                                                const float* __restrict__ bo,
                                                float* __restrict__ out) {
  __shared__ float red[8][16][64];                   // 32 KB K-partials
  __shared__ __align__(16) _Float16 Af[16][72];      // 2.3 KB fp16 tmp tile
  const int t = threadIdx.x, w = t >> 6, l = t & 63;
  const int lr = l & 15, lk8 = (l >> 4) << 3;
  const int r0 = (int)blockIdx.x << 4;

  // ---- phase 1: wave-private K-slice, 4 chunks of k=32 ----
  {
    const float* xp = &x[(r0 + lr) * 1024 + (w << 7) + lk8];
    const half8* bp = (const half8*)BvF;
    f32x4 acc[4] = {};
    float4 xv[2][2];
    xv[0][0] = *(const float4*)(xp);
    xv[0][1] = *(const float4*)(xp + 4);
#pragma unroll
    for (int kc = 0; kc < 4; ++kc) {
      const int cur = kc & 1;
      if (kc + 1 < 4) {  // next x chunk (HBM/L3)
        const float* xq = xp + (kc + 1) * 32;
        xv[cur ^ 1][0] = *(const float4*)(xq);
        xv[cur ^ 1][1] = *(const float4*)(xq + 4);
      }
      half8 br[4];
#pragma unroll
      for (int ct = 0; ct < 4; ++ct)
        br[ct] = bp[((w * 4 + kc) * 4 + ct) * 64 + l];
      const half8 ah = cvt8(xv[cur][0], xv[cur][1]);
#pragma unroll
      for (int ct = 0; ct < 4; ++ct)
        acc[ct] = __builtin_amdgcn_mfma_f32_16x16x32_f16(ah, br[ct], acc[ct], 0, 0, 0);
    }
    // C/D: col = l&15, row = (l>>4)*4 + j  [m89-verified, rounds 3-7 pass]
#pragma unroll
    for (int ct = 0; ct < 4; ++ct)
#pragma unroll
      for (int j = 0; j < 4; ++j)
        red[w][((l >> 4) << 2) + j][(ct << 4) + lr] = acc[ct][j];
  }
  __syncthreads();
  // ---- reduce 8 K-partials -> fp16 tmp tile (512 thr, float2 each) ----
  {
    const int row = t >> 5, c = (t & 31) << 1;
    float sx = 0.f, sy = 0.f;
#pragma unroll
    for (int p = 0; p < 8; ++p) {
      float2 v = *(const float2*)&red[p][row][c];
      sx += v.x; sy += v.y;
    }
    _Float16 hv[2] = {(_Float16)sx, (_Float16)sy};
    *(unsigned int*)&Af[row][c] = *(const unsigned int*)hv;
  }
  __syncthreads();
  // ---- phase 2: cols w*128..+127; operand-swapped MFMA, float4 stores ----
  {
    half8 tfr[2];  // tmp tile as B-operand: lane l -> tmp[row=l&15][d=kk*32+(l>>4)*8+j]
#pragma unroll
    for (int kk = 0; kk < 2; ++kk)
      tfr[kk] = *(const half8*)&Af[lr][kk * 32 + lk8];
    const half8* bp = (const half8*)BoF;
    const int g0 = w << 3;
    half8 wfr[2][2];
    float4 bvr[2];
#pragma unroll
    for (int kk = 0; kk < 2; ++kk)
      wfr[0][kk] = bp[(g0 * 2 + kk) * 64 + l];
    bvr[0] = *(const float4*)&bo[(g0 << 4) + ((l >> 4) << 2)];
#pragma unroll
    for (int g = 0; g < 8; ++g) {
      const int cur = g & 1;
      if (g + 1 < 8) {
#pragma unroll
        for (int kk = 0; kk < 2; ++kk)
          wfr[cur ^ 1][kk] = bp[((g0 + g + 1) * 2 + kk) * 64 + l];
        bvr[cur ^ 1] = *(const float4*)&bo[((g0 + g + 1) << 4) + ((l >> 4) << 2)];
      }
      // D = WoS^T x tmp^T = out^T tile: lane col = x-row (l&15),
      // regs j = 4 consecutive e at (l>>4)*4  => one float4 store per lane.
      f32x4 a = {};
#pragma unroll
      for (int kk = 0; kk < 2; ++kk)
        a = __builtin_amdgcn_mfma_f32_16x16x32_f16(wfr[cur][kk], tfr[kk], a, 0, 0, 0);
      const int col = ((g0 + g) << 4) + ((l >> 4) << 2);
      const float4 bv = bvr[cur];
      float4 o = make_float4(a[0] + bv.x, a[1] + bv.y, a[2] + bv.z, a[3] + bv.w);
      *(float4*)&out[(r0 + lr) * 1024 + col] = o;
    }
  }
}

extern "C" void kernel_launch(void* const* d_in, const int* in_sizes, int n_in,
                              void* d_out, int out_size, void* d_ws, size_t ws_size,
                              hipStream_t stream) {
  const float* x = (const float*)d_in[0];
  // d_in[1] = Wq, d_in[2] = Wk: mathematically dead (softmax rows sum to 1).
  const float* Wv = (const float*)d_in[3];
  const float* Wo = (const float*)d_in[4];
  const float* bo = (const float*)d_in[5];
  float* out = (float*)d_out;

  // ws: BvF 128 KB | BoF 128 KB  (fp16 frags)
  _Float16* BvF = (_Float16*)d_ws;
  _Float16* BoF = BvF + 65536;

  prep<<<96, 256, 0, stream>>>(Wv, Wo, BvF, BoF);
  fused<<<1024, 512, 0, stream>>>(x, BvF, BoF, bo, out);
}

// Round 9
// 142.006 us; speedup vs baseline: 1.1555x; 1.1555x over previous
//
#include <hip/hip_runtime.h>
#include <hip/hip_bf16.h>

// Math (validated rounds 2-8, all passed): softmax rows sum to 1 =>
//   out = (x @ WvSum) @ WoSum + bo,  Wq/Wk dead.
// Numerics: single-product fp16 MFMA (rounds 6-8: absmax 0.125, passed).
// Rounds 6-8 showed: compiler sinks every register prefetch (VGPR 32!) ->
// ~2 loads in flight per wave -> 2-2.6 TB/s no matter the occupancy.
// This round: ALL global loads in phase1/2 are asm volatile (cannot be sunk),
// issued 24-deep per lane, consumed with hand-counted s_waitcnt vmcnt(N) +
// sched_barrier(0) (guide rule #18). vmcnt counts retire in order; counts are
// shift-invariant to compiler-inserted vm ops (extra ops only strengthen the
// wait). Output goes through an LDS bounce -> full-line streaming stores.

typedef _Float16 half8 __attribute__((ext_vector_type(8)));
typedef float f32x4 __attribute__((ext_vector_type(4)));

#define GLOADO(dst, addr, IMM)                                   \
  asm volatile("global_load_dwordx4 %0, %1, off offset:" #IMM    \
               : "=v"(dst) : "v"(addr))

#define WAITVM(N)                                                \
  do {                                                           \
    asm volatile("s_waitcnt vmcnt(" #N ")" ::: "memory");        \
    __builtin_amdgcn_sched_barrier(0);                           \
  } while (0)

__device__ __forceinline__ half8 cvt8(float4 a, float4 b) {
  half8 h;
  h[0] = (_Float16)a.x; h[1] = (_Float16)a.y;
  h[2] = (_Float16)a.z; h[3] = (_Float16)a.w;
  h[4] = (_Float16)b.x; h[5] = (_Float16)b.y;
  h[6] = (_Float16)b.z; h[7] = (_Float16)b.w;
  return h;
}

// ---------------- prep: weight sums -> fp16 B-frags in MFMA lane order -------
// (verbatim rounds 6-8 — verified)
// BvF (half8 idx): (s*4 + ctg)*64 + lane  holds WvSum[k=s*32+(l>>4)*8+j][d=ctg*16+(l&15)]
// BoF (half8 idx): (g*2 + kk)*64 + lane   holds WoSum[k=kk*32+(l>>4)*8+j][e=g*16+(l&15)]
__global__ __launch_bounds__(256) void prep(const float* __restrict__ Wv,
                                            const float* __restrict__ Wo,
                                            _Float16* __restrict__ BvF,
                                            _Float16* __restrict__ BoF) {
  const int b = blockIdx.x, t = threadIdx.x;
  const int l = t & 63, lr = l & 15, lk = (l >> 4) << 3;
  if (b < 32) {                 // Bv frags, k-slice s = b
    const int s = b, ctg = t >> 6;
    const int d = (ctg << 4) + lr;
    const int k0 = (s << 5) + lk;
    float sum[8] = {};
#pragma unroll
    for (int h = 0; h < 16; ++h)
#pragma unroll
      for (int j = 0; j < 8; ++j)
        sum[j] += Wv[(k0 + j) * 1024 + h * 64 + d];
    half8 hv;
#pragma unroll
    for (int j = 0; j < 8; ++j) hv[j] = (_Float16)sum[j];
    ((half8*)BvF)[(s * 4 + ctg) * 64 + l] = hv;
  } else {                      // Bo frags, col-frag g = b-32
    const int g = b - 32;
    const int kk = t >> 7, jh = (t >> 6) & 1;
    const int e = (g << 4) + lr;
    const int kb = (kk << 5) + lk + (jh << 2);
    float sum[4] = {};
#pragma unroll
    for (int h = 0; h < 16; ++h)
#pragma unroll
      for (int j = 0; j < 4; ++j)
        sum[j] += Wo[(h * 64 + kb + j) * 1024 + e];
    _Float16 hv[4];
#pragma unroll
    for (int j = 0; j < 4; ++j) hv[j] = (_Float16)sum[j];
    *(uint2*)&BoF[(((g * 2 + kk) * 64 + l) << 3) + (jh << 2)] =
        *(const uint2*)hv;
  }
}

// ---------------- fused: out_strip = (x_strip @ WvS) @ WoS + bo --------------
// 256 thr = 4 waves (q), strip = 16 rows, grid 1024, 3 blocks/CU.
// Phase1: wave q = K-slice q*256..+255; all loads asm, 24 in flight/lane.
// Phase2: wave q = col-frags (h*32 + q*8 + g); LDS bounce -> full-line stores.
__global__ __launch_bounds__(256, 3) void fused(const float* __restrict__ x,
                                                const _Float16* __restrict__ BvF,
                                                const _Float16* __restrict__ BoF,
                                                const float* __restrict__ bo,
                                                float* __restrict__ out) {
  __shared__ __align__(16) float shbuf[16 * 516];        // red (4KB f32 view) / obuf
  __shared__ __align__(16) _Float16 Af[16][72];
  const int t = threadIdx.x, q = t >> 6, l = t & 63;
  const int lr = l & 15, lk8 = (l >> 4) << 3;
  const int r0 = (int)blockIdx.x << 4;

  // ---- phase 1: acc = x_strip @ WvS, K-slice per wave, asm-pipelined ----
  {
    const char* xb = (const char*)&x[(r0 + lr) * 1024 + (q << 8) + lk8];
    const char* bvb = (const char*)BvF + (((q * 32) * 64) + l) * 16;
    float4 xv[16];
    half8 br[4][4];
    f32x4 acc[4] = {};
    // issue order (24 ops): B0(4), B1(4), x0..x15(16)
    GLOADO(br[0][0], bvb, 0);    GLOADO(br[0][1], bvb, 1024);
    GLOADO(br[0][2], bvb, 2048); GLOADO(br[0][3], bvb, 3072);
    {
      const char* b1 = bvb + 4096;
      GLOADO(br[1][0], b1, 0);    GLOADO(br[1][1], b1, 1024);
      GLOADO(br[1][2], b1, 2048); GLOADO(br[1][3], b1, 3072);
    }
    GLOADO(xv[0], xb, 0);     GLOADO(xv[1], xb, 16);
    GLOADO(xv[2], xb, 128);   GLOADO(xv[3], xb, 144);
    GLOADO(xv[4], xb, 256);   GLOADO(xv[5], xb, 272);
    GLOADO(xv[6], xb, 384);   GLOADO(xv[7], xb, 400);
    GLOADO(xv[8], xb, 512);   GLOADO(xv[9], xb, 528);
    GLOADO(xv[10], xb, 640);  GLOADO(xv[11], xb, 656);
    GLOADO(xv[12], xb, 768);  GLOADO(xv[13], xb, 784);
    GLOADO(xv[14], xb, 896);  GLOADO(xv[15], xb, 912);

    // waits derived from in-order vmcnt retirement; see round notes.
#define CHUNK(c, N)                                                            \
    do {                                                                       \
      if ((c) + 2 < 8) {                                                       \
        const char* bk = bvb + ((c) + 2) * 4096;                               \
        GLOADO(br[((c) + 2) & 3][0], bk, 0);                                   \
        GLOADO(br[((c) + 2) & 3][1], bk, 1024);                                \
        GLOADO(br[((c) + 2) & 3][2], bk, 2048);                                \
        GLOADO(br[((c) + 2) & 3][3], bk, 3072);                                \
      }                                                                        \
      WAITVM(N);                                                               \
      half8 ah = cvt8(xv[2 * (c)], xv[2 * (c) + 1]);                           \
      acc[0] = __builtin_amdgcn_mfma_f32_16x16x32_f16(ah, br[(c) & 3][0], acc[0], 0, 0, 0); \
      acc[1] = __builtin_amdgcn_mfma_f32_16x16x32_f16(ah, br[(c) & 3][1], acc[1], 0, 0, 0); \
      acc[2] = __builtin_amdgcn_mfma_f32_16x16x32_f16(ah, br[(c) & 3][2], acc[2], 0, 0, 0); \
      acc[3] = __builtin_amdgcn_mfma_f32_16x16x32_f16(ah, br[(c) & 3][3], acc[3], 0, 0, 0); \
    } while (0)

    CHUNK(0, 18); CHUNK(1, 16); CHUNK(2, 8); CHUNK(3, 8);
    CHUNK(4, 8);  CHUNK(5, 8);  CHUNK(6, 4); CHUNK(7, 0);
#undef CHUNK
    // C/D: col = l&15, row = (l>>4)*4 + j  [verified rounds 3-8]
#pragma unroll
    for (int ct = 0; ct < 4; ++ct)
#pragma unroll
      for (int j = 0; j < 4; ++j)
        shbuf[((q * 16) + (((l >> 4) << 2) + j)) * 64 + (ct << 4) + lr] = acc[ct][j];
  }
  __syncthreads();
  // ---- reduce 4 K-partials -> fp16 A tile ----
  {
    const int row = t >> 4, c4 = (t & 15) << 2;
    float4 s0 = *(const float4*)&shbuf[(0 * 16 + row) * 64 + c4];
    const float4 s1 = *(const float4*)&shbuf[(1 * 16 + row) * 64 + c4];
    const float4 s2 = *(const float4*)&shbuf[(2 * 16 + row) * 64 + c4];
    const float4 s3 = *(const float4*)&shbuf[(3 * 16 + row) * 64 + c4];
    _Float16 hv[4];
    hv[0] = (_Float16)(s0.x + s1.x + s2.x + s3.x);
    hv[1] = (_Float16)(s0.y + s1.y + s2.y + s3.y);
    hv[2] = (_Float16)(s0.z + s1.z + s2.z + s3.z);
    hv[3] = (_Float16)(s0.w + s1.w + s2.w + s3.w);
    *(uint2*)&Af[row][c4] = *(const uint2*)hv;
  }
  __syncthreads();

  // ---- phase 2: operand-swapped (verified round 8), LDS bounce, 2 halves ----
  half8 tfr[2];
  tfr[0] = *(const half8*)&Af[lr][lk8];
  tfr[1] = *(const half8*)&Af[lr][32 + lk8];
  const int wcol = q << 7;            // wave's 128-col slab within a half
  const int jj4 = (l >> 4) << 2;

  for (int h = 0; h < 2; ++h) {
    // wave q covers col-frags h*32 + q*8 + g, g=0..7
    const char* bob = (const char*)BoF + ((((h * 32 + q * 8) * 2) * 64) + l) * 16;
    half8 wfr[8][2];
    GLOADO(wfr[0][0], bob, 0); GLOADO(wfr[0][1], bob, 1024);
    { const char* a2 = bob + 1 * 2048; GLOADO(wfr[1][0], a2, 0); GLOADO(wfr[1][1], a2, 1024); }
    { const char* a2 = bob + 2 * 2048; GLOADO(wfr[2][0], a2, 0); GLOADO(wfr[2][1], a2, 1024); }
    { const char* a2 = bob + 3 * 2048; GLOADO(wfr[3][0], a2, 0); GLOADO(wfr[3][1], a2, 1024); }
    { const char* a2 = bob + 4 * 2048; GLOADO(wfr[4][0], a2, 0); GLOADO(wfr[4][1], a2, 1024); }
    { const char* a2 = bob + 5 * 2048; GLOADO(wfr[5][0], a2, 0); GLOADO(wfr[5][1], a2, 1024); }
    { const char* a2 = bob + 6 * 2048; GLOADO(wfr[6][0], a2, 0); GLOADO(wfr[6][1], a2, 1024); }
    { const char* a2 = bob + 7 * 2048; GLOADO(wfr[7][0], a2, 0); GLOADO(wfr[7][1], a2, 1024); }

#define PHG(g, N)                                                              \
    do {                                                                       \
      WAITVM(N);                                                               \
      f32x4 a = {};                                                            \
      a = __builtin_amdgcn_mfma_f32_16x16x32_f16(wfr[g][0], tfr[0], a, 0, 0, 0); \
      a = __builtin_amdgcn_mfma_f32_16x16x32_f16(wfr[g][1], tfr[1], a, 0, 0, 0); \
      *(float4*)&shbuf[lr * 516 + wcol + (g) * 16 + jj4] =                     \
          make_float4(a[0], a[1], a[2], a[3]);                                 \
    } while (0)

    PHG(0, 14); PHG(1, 12); PHG(2, 10); PHG(3, 8);
    PHG(4, 6);  PHG(5, 4);  PHG(6, 2);  PHG(7, 0);
#undef PHG
    __syncthreads();
    // stream half h: 16 rows x 512 cols, full-line stores, fused bias
#pragma unroll
    for (int i = 0; i < 8; ++i) {
      const int idx = i * 256 + t;
      const int row = idx >> 7, c4 = (idx & 127) << 2;
      float4 v = *(const float4*)&shbuf[row * 516 + c4];
      float4 bb = *(const float4*)&bo[(h << 9) + c4];
      *(float4*)&out[(r0 + row) * 1024 + (h << 9) + c4] =
          make_float4(v.x + bb.x, v.y + bb.y, v.z + bb.z, v.w + bb.w);
    }
    __syncthreads();
  }
}

extern "C" void kernel_launch(void* const* d_in, const int* in_sizes, int n_in,
                              void* d_out, int out_size, void* d_ws, size_t ws_size,
                              hipStream_t stream) {
  const float* x = (const float*)d_in[0];
  // d_in[1] = Wq, d_in[2] = Wk: mathematically dead (softmax rows sum to 1).
  const float* Wv = (const float*)d_in[3];
  const float* Wo = (const float*)d_in[4];
  const float* bo = (const float*)d_in[5];
  float* out = (float*)d_out;

  // ws: BvF 128 KB | BoF 128 KB  (fp16 frags)
  _Float16* BvF = (_Float16*)d_ws;
  _Float16* BoF = BvF + 65536;

  prep<<<96, 256, 0, stream>>>(Wv, Wo, BvF, BoF);
  fused<<<1024, 256, 0, stream>>>(x, BvF, BoF, bo, out);
}